// Round 2
// baseline (251.096 us; speedup 1.0000x reference)
//
#include <hip/hip_runtime.h>
#include <hip/hip_bf16.h>
#include <cstdio>

#define S_ 1024
#define H_ 1024
#define NH_ 16
#define DH_ 64
#define G_ 100

typedef __attribute__((ext_vector_type(8))) short bf16x8;
typedef __attribute__((ext_vector_type(4))) float f32x4;

__device__ __forceinline__ f32x4 mfma16(bf16x8 a, bf16x8 b, f32x4 c) {
  return __builtin_amdgcn_mfma_f32_16x16x32_bf16(a, b, c, 0, 0, 0);
}

__device__ __forceinline__ short f2bf(float f) {
  union { float f; unsigned int i; } x;
  x.f = f;
  unsigned int r = x.i + 0x7fff + ((x.i >> 16) & 1);  // RNE
  return (short)(r >> 16);
}

// ------- transpose + fp32->bf16 convert, 4 HxH weights: T[n][k] = W[k][n] ---
__global__ __launch_bounds__(256) void transpose_w(
    const float* __restrict__ W0, const float* __restrict__ W1,
    const float* __restrict__ W2, const float* __restrict__ W3,
    short* __restrict__ T0, short* __restrict__ T1,
    short* __restrict__ T2, short* __restrict__ T3) {
  __shared__ short tile[64][72];
  const float* W = (blockIdx.z == 0) ? W0 : (blockIdx.z == 1) ? W1
                 : (blockIdx.z == 2) ? W2 : W3;
  short* T = (blockIdx.z == 0) ? T0 : (blockIdx.z == 1) ? T1
           : (blockIdx.z == 2) ? T2 : T3;
  const int t = threadIdx.x;
  const int r0 = t >> 3;          // 0..31
  const int c8 = (t & 7) * 8;     // 0..56
  const int kbase = blockIdx.x * 64, nbase = blockIdx.y * 64;
#pragma unroll
  for (int p = 0; p < 2; ++p) {
    int r = p * 32 + r0;
    const float* src = W + (size_t)(kbase + r) * H_ + nbase + c8;
    f32x4 u0 = *reinterpret_cast<const f32x4*>(src);
    f32x4 u1 = *reinterpret_cast<const f32x4*>(src + 4);
#pragma unroll
    for (int j = 0; j < 4; ++j) {
      tile[r][c8 + j] = f2bf(u0[j]);
      tile[r][c8 + 4 + j] = f2bf(u1[j]);
    }
  }
  __syncthreads();
#pragma unroll
  for (int p = 0; p < 2; ++p) {
    int r = p * 32 + r0;          // n offset within tile
    bf16x8 o;
#pragma unroll
    for (int j = 0; j < 8; ++j) o[j] = tile[c8 + j][r];
    *reinterpret_cast<bf16x8*>(T + (size_t)(nbase + r) * H_ + kbase + c8) = o;
  }
}

// ---- GEMM: C = A[M,K] @ Bt[N,K]^T + bias; A fp32 or bf16, Bt bf16, acc f32
// AM: 0 = A is fp32, 1 = A is bf16
// OM: 1 = bf16 head layout [B,NH,S,DH]; 2 = bf16 headT [B,NH,DH,S];
//     3 = fp32 flat [M,N]
template <int AM, int OM>
__global__ __launch_bounds__(256) void gemm_bt(
    const void* __restrict__ Av, const short* __restrict__ Bt,
    const float* __restrict__ bias, short* __restrict__ Cb,
    float* __restrict__ Cf, int M, int N, int K) {
  __shared__ short As[128][40];
  __shared__ short Bs[64][40];
  const int t = threadIdx.x;
  const int l = t & 63, w = t >> 6;
  const int lr = l & 15, lg = l >> 4;
  const int wm = w >> 1, wn = w & 1;    // 2x2 waves, each 64 rows x 32 cols
  const int bm = blockIdx.x * 128, bn = blockIdx.y * 64;
  f32x4 acc[4][2];
#pragma unroll
  for (int i = 0; i < 4; ++i)
#pragma unroll
    for (int j = 0; j < 2; ++j) acc[i][j] = (f32x4){0.f, 0.f, 0.f, 0.f};
  const int srow = t >> 2;            // 0..63
  const int koff = (t & 3) * 8;       // 0..24
  for (int kb = 0; kb < K; kb += 32) {
    if constexpr (AM == 0) {
      const float* A = (const float*)Av;
#pragma unroll
      for (int p = 0; p < 2; ++p) {
        int r = p * 64 + srow;
        const float* src = A + (size_t)(bm + r) * K + kb + koff;
        f32x4 u0 = *reinterpret_cast<const f32x4*>(src);
        f32x4 u1 = *reinterpret_cast<const f32x4*>(src + 4);
        bf16x8 o;
#pragma unroll
        for (int j = 0; j < 4; ++j) {
          o[j] = f2bf(u0[j]);
          o[4 + j] = f2bf(u1[j]);
        }
        *reinterpret_cast<bf16x8*>(&As[r][koff]) = o;
      }
    } else {
      const short* A = (const short*)Av;
#pragma unroll
      for (int p = 0; p < 2; ++p) {
        int r = p * 64 + srow;
        *reinterpret_cast<bf16x8*>(&As[r][koff]) =
            *reinterpret_cast<const bf16x8*>(A + (size_t)(bm + r) * K + kb + koff);
      }
    }
    *reinterpret_cast<bf16x8*>(&Bs[srow][koff]) =
        *reinterpret_cast<const bf16x8*>(Bt + (size_t)(bn + srow) * K + kb + koff);
    __syncthreads();
    bf16x8 af[4], bfr[2];
#pragma unroll
    for (int mi = 0; mi < 4; ++mi)
      af[mi] = *reinterpret_cast<const bf16x8*>(&As[wm * 64 + mi * 16 + lr][lg * 8]);
#pragma unroll
    for (int ni = 0; ni < 2; ++ni)
      bfr[ni] = *reinterpret_cast<const bf16x8*>(&Bs[wn * 32 + ni * 16 + lr][lg * 8]);
#pragma unroll
    for (int mi = 0; mi < 4; ++mi)
#pragma unroll
      for (int ni = 0; ni < 2; ++ni)
        acc[mi][ni] = mfma16(af[mi], bfr[ni], acc[mi][ni]);
    __syncthreads();
  }
#pragma unroll
  for (int mi = 0; mi < 4; ++mi)
#pragma unroll
    for (int ni = 0; ni < 2; ++ni) {
      int col = bn + wn * 32 + ni * 16 + lr;
      float bv = bias[col];
#pragma unroll
      for (int r = 0; r < 4; ++r) {
        int row = bm + wm * 64 + mi * 16 + lg * 4 + r;
        float val = acc[mi][ni][r] + bv;
        if constexpr (OM == 3) {
          Cf[(size_t)row * N + col] = val;
        } else {
          int b = row >> 10, s = row & 1023;
          int h = col >> 6, d = col & 63;
          size_t idx;
          if constexpr (OM == 1)
            idx = (((size_t)(b * NH_ + h)) * S_ + s) * DH_ + d;
          else
            idx = (((size_t)(b * NH_ + h)) * DH_ + d) * S_ + s;
          Cb[idx] = f2bf(val);
        }
      }
    }
}

// ---------------- flash attention over heads ------------------------------
// Qh,Kh: [B*NH][S][DH] bf16; VhT: [B*NH][DH][S] bf16; ctx out: [B][S][H] bf16
__global__ __launch_bounds__(256) void attn(
    const short* __restrict__ Qh, const short* __restrict__ Kh,
    const short* __restrict__ VhT, const float* __restrict__ graph,
    const int* __restrict__ mask, short* __restrict__ ctx) {
  __shared__ short P[4][16][72];   // per-wave P tile: [q=16][k=64], padded
  __shared__ float sfb[4][16];
  __shared__ float llb[4][16];
  const int bh = blockIdx.x, qt = blockIdx.y;
  const int b = bh >> 4, h = bh & 15;
  const int t = threadIdx.x, w = t >> 6, l = t & 63;
  const int lr = l & 15, lg = l >> 4;
  const int q0 = qt * 64 + w * 16;      // this wave's q base
  const int qg = q0 + lr;               // lane's q (score layout: col = q)
  const short* Qrow = Qh + ((size_t)bh * S_ + qg) * DH_;
  bf16x8 qf0 = *reinterpret_cast<const bf16x8*>(Qrow + lg * 8);
  bf16x8 qf1 = *reinterpret_cast<const bf16x8*>(Qrow + 32 + lg * 8);
  f32x4 o[4];
#pragma unroll
  for (int i = 0; i < 4; ++i) o[i] = (f32x4){0.f, 0.f, 0.f, 0.f};
  float mrun = -3.0e38f, ll = 0.f;

  for (int kc = 0; kc < S_; kc += 64) {
    // --- swapped QK^T: St[k][q] = K_chunk @ Q^T, lane holds q=lr, k per reg
    f32x4 sacc[4];
#pragma unroll
    for (int mf = 0; mf < 4; ++mf) {
      const short* Krow = Kh + ((size_t)bh * S_ + kc + mf * 16 + lr) * DH_;
      bf16x8 k0 = *reinterpret_cast<const bf16x8*>(Krow + lg * 8);
      bf16x8 k1 = *reinterpret_cast<const bf16x8*>(Krow + 32 + lg * 8);
      f32x4 sa = (f32x4){0.f, 0.f, 0.f, 0.f};
      sa = mfma16(k0, qf0, sa);
      sa = mfma16(k1, qf1, sa);
      sacc[mf] = sa;
    }
    // --- scale, graph factor, mask, online softmax
    float p[16];
    float pmax = -3.0e38f;
#pragma unroll
    for (int mf = 0; mf < 4; ++mf)
#pragma unroll
      for (int r = 0; r < 4; ++r) {
        float s = sacc[mf][r] * 0.125f;
        int kg = kc + mf * 16 + lg * 4 + r;
        if (qg < G_ && kg < G_)
          s *= (1.f - graph[((size_t)b * G_ + qg) * G_ + kg]);
        if (mask[b * S_ + kg] != 0) s = -1.0e9f;
        p[mf * 4 + r] = s;
        pmax = fmaxf(pmax, s);
      }
    pmax = fmaxf(pmax, __shfl_xor(pmax, 16));
    pmax = fmaxf(pmax, __shfl_xor(pmax, 32));
    float mnew = fmaxf(mrun, pmax);
    float sf = __expf(mrun - mnew);
    float psum = 0.f;
#pragma unroll
    for (int i = 0; i < 16; ++i) {
      float e = __expf(p[i] - mnew);
      p[i] = e;
      psum += e;
    }
    psum += __shfl_xor(psum, 16);
    psum += __shfl_xor(psum, 32);
    ll = ll * sf + psum;
    mrun = mnew;
    if (lg == 0) sfb[w][lr] = sf;
#pragma unroll
    for (int mf = 0; mf < 4; ++mf)
#pragma unroll
      for (int r = 0; r < 4; ++r)
        P[w][lr][mf * 16 + lg * 4 + r] = f2bf(p[mf * 4 + r]);
    __syncthreads();
    // --- rescale O rows (O layout: row q = lg*4+r, col d = nf*16+lr)
    float srow[4];
#pragma unroll
    for (int r = 0; r < 4; ++r) srow[r] = sfb[w][lg * 4 + r];
#pragma unroll
    for (int nf = 0; nf < 4; ++nf)
#pragma unroll
      for (int r = 0; r < 4; ++r) o[nf][r] *= srow[r];
    // --- PV: O[16q][64d] += P[16q,64k] @ V[64k,64d]  (B^T = VhT rows)
#pragma unroll
    for (int ks = 0; ks < 2; ++ks) {
      bf16x8 pa = *reinterpret_cast<const bf16x8*>(&P[w][lr][ks * 32 + lg * 8]);
#pragma unroll
      for (int nf = 0; nf < 4; ++nf) {
        const short* Vrow = VhT + ((size_t)bh * DH_ + nf * 16 + lr) * S_ +
                            kc + ks * 32 + lg * 8;
        bf16x8 vb = *reinterpret_cast<const bf16x8*>(Vrow);
        o[nf] = mfma16(pa, vb, o[nf]);
      }
    }
    __syncthreads();
  }
  if (lg == 0) llb[w][lr] = ll;
  __syncthreads();
  float lrow[4];
#pragma unroll
  for (int r = 0; r < 4; ++r) lrow[r] = llb[w][lg * 4 + r];
#pragma unroll
  for (int nf = 0; nf < 4; ++nf)
#pragma unroll
    for (int r = 0; r < 4; ++r) {
      float val = o[nf][r] / lrow[r];
      ctx[((size_t)b * S_ + q0 + lg * 4 + r) * H_ + h * DH_ + nf * 16 + lr] =
          f2bf(val);
    }
}

extern "C" void kernel_launch(void* const* d_in, const int* in_sizes, int n_in,
                              void* d_out, int out_size, void* d_ws, size_t ws_size,
                              hipStream_t stream) {
  const int B = in_sizes[0] / (S_ * H_);   // 4
  const int M = B * S_;                    // 4096
  const float* v    = (const float*)d_in[0];
  const float* k    = (const float*)d_in[1];
  const float* q    = (const float*)d_in[2];
  const int*   mask = (const int*)d_in[3];
  const float* graph= (const float*)d_in[4];
  const float* Wq   = (const float*)d_in[5];
  const float* bq   = (const float*)d_in[6];
  const float* Wk   = (const float*)d_in[7];
  const float* bk   = (const float*)d_in[8];
  const float* Wv   = (const float*)d_in[9];
  const float* bv   = (const float*)d_in[10];
  const float* Wm   = (const float*)d_in[11];
  const float* bm   = (const float*)d_in[12];

  short* ws = (short*)d_ws;
  const size_t WSZ = (size_t)H_ * H_;     // 1M elems per transposed weight
  const size_t TSZ = (size_t)M * H_;      // 4M elems per activation tensor
  short* WqT = ws;
  short* WkT = ws + WSZ;
  short* WvT = ws + 2 * WSZ;
  short* WmT = ws + 3 * WSZ;
  short* Qh  = ws + 4 * WSZ;
  short* Kh  = Qh + TSZ;
  short* VhT = Kh + TSZ;
  short* ctx = VhT + TSZ;
  if (ws_size < (4 * WSZ + 4 * TSZ) * sizeof(short)) {
    fprintf(stderr, "kernel_launch: ws too small (%zu)\n", ws_size);
    return;
  }

  transpose_w<<<dim3(H_ / 64, H_ / 64, 4), 256, 0, stream>>>(
      Wq, Wk, Wv, Wm, WqT, WkT, WvT, WmT);
  gemm_bt<0, 1><<<dim3(M / 128, H_ / 64), 256, 0, stream>>>(
      (const void*)q, WqT, bq, Qh, nullptr, M, H_, H_);
  gemm_bt<0, 1><<<dim3(M / 128, H_ / 64), 256, 0, stream>>>(
      (const void*)k, WkT, bk, Kh, nullptr, M, H_, H_);
  gemm_bt<0, 2><<<dim3(M / 128, H_ / 64), 256, 0, stream>>>(
      (const void*)v, WvT, bv, VhT, nullptr, M, H_, H_);
  attn<<<dim3(B * NH_, S_ / 64), 256, 0, stream>>>(Qh, Kh, VhT, graph, mask, ctx);
  gemm_bt<1, 3><<<dim3(M / 128, H_ / 64), 256, 0, stream>>>(
      (const void*)ctx, WmT, bm, nullptr, (float*)d_out, M, H_, H_);
}